// Round 1
// baseline (949.233 us; speedup 1.0000x reference)
//
#include <hip/hip_runtime.h>

#define NN 50000
#define NE 800000
#define ETOT (NE + NN)
#define GG 1000
#define DD 96
#define HEADS 4
#define DHH 24
#define NL 3

// ---------------- CSR build ----------------
__global__ void count_deg(const int* __restrict__ ei, int* __restrict__ deg) {
    int j = blockIdx.x * blockDim.x + threadIdx.x;
    if (j >= ETOT) return;
    int dst = (j < NE) ? ei[NE + j] : (j - NE);
    atomicAdd(&deg[dst], 1);
}

__global__ void scan_deg(const int* __restrict__ deg, int* __restrict__ row_start) {
    __shared__ int part[1024];
    int t = threadIdx.x;
    const int chunk = (NN + 1023) / 1024;  // 49
    int lo = t * chunk;
    int hi = lo + chunk; if (hi > NN) hi = NN;
    int s = 0;
    for (int i = lo; i < hi; i++) s += deg[i];
    part[t] = s;
    __syncthreads();
    if (t == 0) {
        int run = 0;
        for (int i = 0; i < 1024; i++) { int v = part[i]; part[i] = run; run += v; }
        row_start[NN] = run;  // == ETOT
    }
    __syncthreads();
    int run = part[t];
    for (int i = lo; i < hi; i++) { row_start[i] = run; run += deg[i]; }
}

__global__ void scatter_edges(const int* __restrict__ ei, const int* __restrict__ row_start,
                              int* __restrict__ wcount, int* __restrict__ ssrc) {
    int j = blockIdx.x * blockDim.x + threadIdx.x;
    if (j >= ETOT) return;
    int src, dst;
    if (j < NE) { src = ei[j]; dst = ei[NE + j]; }
    else        { src = j - NE; dst = src; }
    int pos = atomicAdd(&wcount[dst], 1);
    ssrc[row_start[dst] + pos] = src;
}

// ---------------- GEMM: out[N,96] = A[N,96] @ W[96,96] (+bias) ----------------
// 192 threads: 8 rows x 24 col-groups (float4). W staged in LDS.
__global__ __launch_bounds__(192) void gemm96(const float* __restrict__ A,
                                              const float* __restrict__ W,
                                              const float* __restrict__ bias,
                                              float* __restrict__ out) {
    __shared__ float Wl[96 * 96];
    __shared__ float As[8 * 96];
    int t = threadIdx.x;
    const float4* W4 = (const float4*)W;
    float4* Wl4 = (float4*)Wl;
#pragma unroll
    for (int i = 0; i < 12; i++) Wl4[t + 192 * i] = W4[t + 192 * i];
    ((float4*)As)[t] = ((const float4*)(A + (size_t)blockIdx.x * 768))[t];
    __syncthreads();

    int row = t / 24;
    int c = t % 24;
    const float* ar = As + row * 96;
    float4 acc = make_float4(0.f, 0.f, 0.f, 0.f);
#pragma unroll
    for (int k = 0; k < 96; k++) {
        float a = ar[k];
        float4 w = ((const float4*)(Wl + k * 96))[c];
        acc.x += a * w.x; acc.y += a * w.y; acc.z += a * w.z; acc.w += a * w.w;
    }
    if (bias) {
        float4 b = ((const float4*)bias)[c];
        acc.x += b.x; acc.y += b.y; acc.z += b.z; acc.w += b.w;
    }
    ((float4*)(out + ((size_t)blockIdx.x * 8 + row) * 96))[c] = acc;
}

// ---------------- per-node attention logits ----------------
// thread per (node, head): two length-24 dots
__global__ void alpha_kernel(const float* __restrict__ h,
                             const float* __restrict__ a_s, const float* __restrict__ a_d,
                             float* __restrict__ as_out, float* __restrict__ ad_out) {
    int id = blockIdx.x * blockDim.x + threadIdx.x;  // n*4 + head
    if (id >= NN * HEADS) return;
    int hh = id & 3;
    const float* hp = h + (size_t)id * DHH;  // n*96 + hh*24 == id*24
    const float* asv = a_s + hh * DHH;
    const float* adv = a_d + hh * DHH;
    float s1 = 0.f, s2 = 0.f;
#pragma unroll
    for (int k = 0; k < DHH; k++) { float v = hp[k]; s1 += v * asv[k]; s2 += v * adv[k]; }
    as_out[id] = s1;
    ad_out[id] = s2;
}

// ---------------- softmax-weighted aggregation + bias + BN + ReLU ----------------
// 192 threads = 2 nodes x 96 dims. Each lane owns one output dim; softmax stats
// computed redundantly per-lane (all lanes of a head see identical e values).
__global__ __launch_bounds__(192) void aggregate(const float* __restrict__ hB,
                                                 const int* __restrict__ row_start,
                                                 const int* __restrict__ ssrc,
                                                 const float* __restrict__ asv,
                                                 const float* __restrict__ adv,
                                                 const float* __restrict__ bc,
                                                 const float* __restrict__ gamma,
                                                 const float* __restrict__ beta,
                                                 const float* __restrict__ mean,
                                                 const float* __restrict__ var,
                                                 float* __restrict__ out) {
    int t = threadIdx.x;
    int n = blockIdx.x * 2 + t / 96;
    int d = t % 96;
    int hh = d / 24;
    int start = row_start[n];
    int end = row_start[n + 1];
    float ad = adv[n * 4 + hh];

    float m = -1e30f;
    for (int j = start; j < end; j++) {
        int s = ssrc[j];
        float e = asv[s * 4 + hh] + ad;
        e = (e >= 0.f) ? e : 0.2f * e;
        m = fmaxf(m, e);
    }
    float sw = 0.f, acc = 0.f;
    for (int j = start; j < end; j++) {
        int s = ssrc[j];
        float e = asv[s * 4 + hh] + ad;
        e = (e >= 0.f) ? e : 0.2f * e;
        float w = expf(e - m);
        sw += w;
        acc += w * hB[(size_t)s * DD + d];
    }
    float o = acc / (sw + 1e-16f) + bc[d];
    o = (o - mean[d]) * (1.0f / sqrtf(var[d] + 1e-5f)) * gamma[d] + beta[d];
    out[(size_t)n * DD + d] = fmaxf(o, 0.f);
}

// ---------------- global mean pool (atomic) ----------------
__global__ void pool_kernel(const float* __restrict__ h, const int* __restrict__ batch,
                            float* __restrict__ pooled, float* __restrict__ cnt) {
    int i = blockIdx.x * blockDim.x + threadIdx.x;
    if (i >= NN * DD) return;
    int n = i / DD;
    int d = i - n * DD;
    int b = batch[n];
    atomicAdd(&pooled[b * DD + d], h[i]);
    if (d == 0) atomicAdd(&cnt[b], 1.0f);
}

// ---------------- output MLP: one block per graph ----------------
__global__ __launch_bounds__(128) void mlp_kernel(const float* __restrict__ pooled,
                                                  const float* __restrict__ cnt,
                                                  const float* __restrict__ W1, const float* __restrict__ b1,
                                                  const float* __restrict__ W2, const float* __restrict__ b2,
                                                  const float* __restrict__ W3, const float* __restrict__ b3,
                                                  float* __restrict__ out) {
    __shared__ float p[96], z1[96], z2[48];
    int g = blockIdx.x, t = threadIdx.x;
    if (t < 96) p[t] = pooled[g * 96 + t] / fmaxf(cnt[g], 1.0f);
    __syncthreads();
    if (t < 96) {
        float s = b1[t];
#pragma unroll
        for (int k = 0; k < 96; k++) s += p[k] * W1[k * 96 + t];
        z1[t] = fmaxf(s, 0.f);
    }
    __syncthreads();
    if (t < 48) {
        float s = b2[t];
#pragma unroll
        for (int k = 0; k < 96; k++) s += z1[k] * W2[k * 48 + t];
        z2[t] = fmaxf(s, 0.f);
    }
    __syncthreads();
    if (t == 0) {
        float s = b3[0];
        for (int k = 0; k < 48; k++) s += z2[k] * W3[k];
        out[g] = s;
    }
}

extern "C" void kernel_launch(void* const* d_in, const int* in_sizes, int n_in,
                              void* d_out, int out_size, void* d_ws, size_t ws_size,
                              hipStream_t stream) {
    const float* x        = (const float*)d_in[0];
    const int*   ei       = (const int*)d_in[1];
    const int*   batch    = (const int*)d_in[2];
    const float* Wp       = (const float*)d_in[3];
    const float* bp       = (const float*)d_in[4];
    const float* Wc       = (const float*)d_in[5];
    const float* att_src  = (const float*)d_in[6];
    const float* att_dst  = (const float*)d_in[7];
    const float* bc       = (const float*)d_in[8];
    const float* bn_gamma = (const float*)d_in[9];
    const float* bn_beta  = (const float*)d_in[10];
    const float* bn_mean  = (const float*)d_in[11];
    const float* bn_var   = (const float*)d_in[12];
    const float* W1       = (const float*)d_in[13];
    const float* b1       = (const float*)d_in[14];
    const float* W2       = (const float*)d_in[15];
    const float* b2       = (const float*)d_in[16];
    const float* W3       = (const float*)d_in[17];
    const float* b3       = (const float*)d_in[18];
    float* out = (float*)d_out;

    char* ws = (char*)d_ws;
    auto alloc = [&](size_t bytes) {
        void* p = (void*)ws;
        ws += (bytes + 255) & ~(size_t)255;
        return p;
    };
    float* hA        = (float*)alloc((size_t)NN * DD * 4);
    float* hB        = (float*)alloc((size_t)NN * DD * 4);
    float* as_       = (float*)alloc((size_t)NN * HEADS * 4);
    float* ad_       = (float*)alloc((size_t)NN * HEADS * 4);
    int*   deg       = (int*)alloc((size_t)NN * 4);
    int*   wcount    = (int*)alloc((size_t)NN * 4);
    int*   row_start = (int*)alloc((size_t)(NN + 1) * 4);
    int*   ssrc      = (int*)alloc((size_t)ETOT * 4);
    float* pooled    = (float*)alloc((size_t)GG * DD * 4);
    float* cnt       = (float*)alloc((size_t)GG * 4);

    hipMemsetAsync(deg, 0, (size_t)NN * 4, stream);
    hipMemsetAsync(wcount, 0, (size_t)NN * 4, stream);
    hipMemsetAsync(pooled, 0, (size_t)GG * DD * 4, stream);
    hipMemsetAsync(cnt, 0, (size_t)GG * 4, stream);

    count_deg<<<(ETOT + 255) / 256, 256, 0, stream>>>(ei, deg);
    scan_deg<<<1, 1024, 0, stream>>>(deg, row_start);
    scatter_edges<<<(ETOT + 255) / 256, 256, 0, stream>>>(ei, row_start, wcount, ssrc);

    // input projection
    gemm96<<<NN / 8, 192, 0, stream>>>(x, Wp, bp, hA);

    for (int l = 0; l < NL; l++) {
        gemm96<<<NN / 8, 192, 0, stream>>>(hA, Wc + (size_t)l * DD * DD, nullptr, hB);
        alpha_kernel<<<(NN * HEADS + 255) / 256, 256, 0, stream>>>(
            hB, att_src + (size_t)l * HEADS * DHH, att_dst + (size_t)l * HEADS * DHH, as_, ad_);
        aggregate<<<NN / 2, 192, 0, stream>>>(hB, row_start, ssrc, as_, ad_,
                                              bc + (size_t)l * DD,
                                              bn_gamma + (size_t)l * DD, bn_beta + (size_t)l * DD,
                                              bn_mean + (size_t)l * DD, bn_var + (size_t)l * DD,
                                              hA);
    }

    pool_kernel<<<(NN * DD + 255) / 256, 256, 0, stream>>>(hA, batch, pooled, cnt);
    mlp_kernel<<<GG, 128, 0, stream>>>(pooled, cnt, W1, b1, W2, b2, W3, b3, out);
}